// Round 12
// baseline (2316.068 us; speedup 1.0000x reference)
//
#include <hip/hip_runtime.h>
#include <hip/hip_bf16.h>

typedef unsigned short ushortT;
typedef __attribute__((ext_vector_type(8))) short bf16x8;
typedef __attribute__((ext_vector_type(4))) float f32x4;
typedef __attribute__((ext_vector_type(4))) int i32x4;

#define B_SZ 64
#define T_SZ 512
#define D_SZ 256
#define U_SZ 512
#define M_SZ 64

// ---------- helpers ----------
__device__ __forceinline__ ushortT f2b(float f) {
    __hip_bfloat16 h = __float2bfloat16(f);
    union { __hip_bfloat16 h; ushortT u; } c; c.h = h; return c.u;
}
__device__ __forceinline__ float clip10(float v) {
    return fminf(fmaxf(v, -10.f), 10.f);
}
__device__ __forceinline__ float tanh_fast(float z) {
    float e = __expf(2.f * z);
    return 1.f - 2.f / (e + 1.f);   // inf-safe
}
__device__ __forceinline__ float sigm_fast(float z) {
    return 1.f / (1.f + __expf(-z));
}

// ---------- prep: x -> clipped bf16 ----------
__global__ void prep_xb_k(const float* __restrict__ x, ushortT* __restrict__ xb) {
    const int n4 = (B_SZ * T_SZ * D_SZ) / 4;
    for (int i = blockIdx.x * blockDim.x + threadIdx.x; i < n4; i += gridDim.x * blockDim.x) {
        float4 v = ((const float4*)x)[i];
        ushort4 o;
        o.x = f2b(clip10(v.x));
        o.y = f2b(clip10(v.y));
        o.z = f2b(clip10(v.z));
        o.w = f2b(clip10(v.w));
        ((ushort4*)xb)[i] = o;
    }
}

// ---------- prep: U^T and W^T bf16 (transposed, col-major rows) ----------
// UslT cols: 0..2047 gate U cols, 2048..2111 Ue cols.
// WslT cols: 0..2047 gate W cols, 2048..2111 We cols, 2112..2623 Wm cols.
__global__ void prep_uw_k(const float* __restrict__ Ui, const float* __restrict__ Uf,
                          const float* __restrict__ Uo, const float* __restrict__ Uc,
                          const float* __restrict__ Ue,
                          const float* __restrict__ Wi, const float* __restrict__ Wf,
                          const float* __restrict__ Wo, const float* __restrict__ Wc,
                          const float* __restrict__ We, const float* __restrict__ Wm,
                          ushortT* __restrict__ UslT, ushortT* __restrict__ WslT) {
    const int NU = 2112 * 512;
    const int NW = 2624 * 256;
    for (int i = blockIdx.x * blockDim.x + threadIdx.x; i < NU + NW; i += gridDim.x * blockDim.x) {
        if (i < NU) {
            int c = i >> 9, k = i & 511;
            float v;
            if (c < 2048) {
                int g = c >> 9, u = c & 511;
                const float* U = (g == 0) ? Ui : (g == 1) ? Uf : (g == 2) ? Uo : Uc;
                v = U[k * 512 + u];
            } else {
                v = Ue[k * 64 + (c - 2048)];
            }
            UslT[i] = f2b(v);
        } else {
            int j = i - NU;
            int c = j >> 8, k = j & 255;
            float v;
            if (c < 2048) {
                int g = c >> 9, u = c & 511;
                const float* W = (g == 0) ? Wi : (g == 1) ? Wf : (g == 2) ? Wo : Wc;
                v = W[k * 512 + u];
            } else if (c < 2112) {
                v = We[k * 64 + (c - 2048)];
            } else {
                v = Wm[k * 512 + (c - 2112)];
            }
            WslT[j] = f2b(v);
        }
    }
}

#define MEMF_PB 1096   // floats per batch block (16 rows x 68 + 8 skew)
#define MEMF_ROW 68

// ---------- persistent recurrent kernel ----------
// Structure = R9 (proven: 2303us, absmax 0.0083) with ONE change: the poll is
// sentinel-gated. Each lane polls word 0 of its own 64B granule (4B/iter vs
// 64B), then bulk-reads the granule and RE-VALIDATES all 16 tags (retry on
// stale). Tags are self-validating per u32 (tag<<16 | bf16), so no line-
// atomicity assumption. All sync through LLC (sc0 sc1) — G16-safe.
__global__ __launch_bounds__(256, 1) void xlstm_rec(
    const ushortT* __restrict__ xb,    // [B*T][256] bf16 (clipped)
    const ushortT* __restrict__ UslT,  // [2112][512] bf16
    const ushortT* __restrict__ WslT,  // [2624][256] bf16
    const float* __restrict__ bi_p, const float* __restrict__ bf_p,
    const float* __restrict__ bo_p, const float* __restrict__ bc_p,
    const float* __restrict__ be_p,
    unsigned* __restrict__ Hbuf32,     // [2][64][512] u32 tagged h
    float* __restrict__ out)           // [64][512][512] fp32
{
    const int bid = blockIdx.x, tid = threadIdx.x;
    const int grp = bid & 7, rank = bid >> 3;
    const int wave = tid >> 6, lane = tid & 63;
    const int b0 = grp << 3;     // batch base
    const int u0 = rank << 4;    // unit base

    __shared__ float memF[8 * MEMF_PB];     // c ring: [pb][pu][slot(64)+pad] (thread-private rows)
    __shared__ float g_lds[4][8][16];       // i,f,o,ctilde
    __shared__ float e_lds[8][68];          // raw clipped e-logits (logical idx)
    __shared__ float w_lds[8][72];          // softmax numerators (physical slot)
    __shared__ float zm_lds[8][16];         // x_t @ Wm slice
    __shared__ ushortT hLb[8][520];         // h tile bf16, padded stride (1040B)

    for (int i = tid; i < 8 * MEMF_PB; i += 256) memF[i] = 0.f;

    // ---- register-resident weight B-fragments ----
    int cols[2];
    float biasv[2];
#pragma unroll
    for (int nt = 0; nt < 2; ++nt) {
        int j = wave * 32 + nt * 16 + (lane & 15);
        if (j < 64) {
            int g = j >> 4, u = u0 + (j & 15);
            cols[nt] = g * 512 + u;
            biasv[nt] = (g == 0) ? bi_p[u] : (g == 1) ? bf_p[u] : (g == 2) ? bo_p[u] : bc_p[u];
        } else {
            cols[nt] = 2048 + (j - 64);
            biasv[nt] = be_p[j - 64];
        }
    }
    const int koct = (lane >> 4) * 8;
    bf16x8 B1[2][8], B2[2][16], B1m[8];
#pragma unroll
    for (int nt = 0; nt < 2; ++nt) {
        const ushortT* bw = WslT + cols[nt] * 256;
#pragma unroll
        for (int kt = 0; kt < 8; ++kt)
            B1[nt][kt] = *(const bf16x8*)(bw + kt * 32 + koct);
        const ushortT* bu = UslT + cols[nt] * 512;
#pragma unroll
        for (int kt = 0; kt < 16; ++kt)
            B2[nt][kt] = *(const bf16x8*)(bu + kt * 32 + koct);
    }
    if (wave == 1) {   // Wm fragment (zm = x@Wm via MFMA)
        const ushortT* bm = WslT + (2112 + u0 + (lane & 15)) * 256;
#pragma unroll
        for (int kt = 0; kt < 8; ++kt)
            B1m[kt] = *(const bf16x8*)(bm + kt * 32 + koct);
    }

    const int arow = lane & 7;                 // MFMA A-operand batch row
    const bool is_pw = (tid >= 64 && tid < 192);
    const int pb = (tid - 64) >> 4;
    const int pu = (tid - 64) & 15;
    // cooperative tagged-h fetch: wave w owns rows 2w (lanes<32), 2w+1 (lanes>=32)
    const int prow = 2 * wave + (lane >> 5);
    const int pcol = (lane & 31) * 16;         // 16 u32 units per lane (one 64B line)

    __syncthreads();

    for (int t = 0; t < T_SZ; ++t) {
        const int par = t & 1, wpar = (t + 1) & 1;

        // ---- phase A: issue a1f x-fragment loads (overlap with poll) ----
        i32x4 a1f[8];
        {
            const ushortT* xrow = xb + ((b0 + arow) * T_SZ + t) * D_SZ + koct;
#pragma unroll
            for (int kt = 0; kt < 8; ++kt)
                asm volatile("global_load_dwordx4 %0, %1, off"
                             : "=v"(a1f[kt]) : "v"(xrow + kt * 32));
        }

        // ---- phase B1: sentinel poll (4B/lane/iter; also drains a1f/old stores) ----
        const unsigned* hsrc = Hbuf32 + (par << 15) + (b0 + prow) * 512 + pcol;
        const unsigned T16 = ((unsigned)t) << 16;
        while (true) {
            unsigned s;
            asm volatile("global_load_dword %0, %1, off sc0 sc1\n\t"
                         "s_waitcnt vmcnt(0)"
                         : "=v"(s) : "v"(hsrc) : "memory");
            if (__all(((s ^ T16) & 0xFFFF0000u) == 0u)) break;
        }
        // ---- phase B2: bulk read own 64B line + full tag validation ----
        i32x4 g0, g1, g2, g3;
        while (true) {
            asm volatile("global_load_dwordx4 %0, %4, off sc0 sc1\n\t"
                         "global_load_dwordx4 %1, %4, off offset:16 sc0 sc1\n\t"
                         "global_load_dwordx4 %2, %4, off offset:32 sc0 sc1\n\t"
                         "global_load_dwordx4 %3, %4, off offset:48 sc0 sc1\n\t"
                         "s_waitcnt vmcnt(0)"
                         : "=v"(g0), "=v"(g1), "=v"(g2), "=v"(g3)
                         : "v"(hsrc) : "memory");
            unsigned d = (((unsigned)g0[0] ^ T16) | ((unsigned)g0[1] ^ T16)) |
                         (((unsigned)g0[2] ^ T16) | ((unsigned)g0[3] ^ T16));
            d |= (((unsigned)g1[0] ^ T16) | ((unsigned)g1[1] ^ T16)) |
                 (((unsigned)g1[2] ^ T16) | ((unsigned)g1[3] ^ T16));
            d |= (((unsigned)g2[0] ^ T16) | ((unsigned)g2[1] ^ T16)) |
                 (((unsigned)g2[2] ^ T16) | ((unsigned)g2[3] ^ T16));
            d |= (((unsigned)g3[0] ^ T16) | ((unsigned)g3[1] ^ T16)) |
                 (((unsigned)g3[2] ^ T16) | ((unsigned)g3[3] ^ T16));
            if (__all((d & 0xFFFF0000u) == 0u)) break;
        }
        __builtin_amdgcn_sched_barrier(0);

        // ---- phase C: strip tags, pack bf16 pairs, stage into LDS ----
        {
            unsigned p0 = ((unsigned)g0[0] & 0xFFFFu) | ((unsigned)g0[1] << 16);
            unsigned p1 = ((unsigned)g0[2] & 0xFFFFu) | ((unsigned)g0[3] << 16);
            unsigned p2 = ((unsigned)g1[0] & 0xFFFFu) | ((unsigned)g1[1] << 16);
            unsigned p3 = ((unsigned)g1[2] & 0xFFFFu) | ((unsigned)g1[3] << 16);
            unsigned p4 = ((unsigned)g2[0] & 0xFFFFu) | ((unsigned)g2[1] << 16);
            unsigned p5 = ((unsigned)g2[2] & 0xFFFFu) | ((unsigned)g2[3] << 16);
            unsigned p6 = ((unsigned)g3[0] & 0xFFFFu) | ((unsigned)g3[1] << 16);
            unsigned p7 = ((unsigned)g3[2] & 0xFFFFu) | ((unsigned)g3[3] << 16);
            i32x4 P0 = {(int)p0, (int)p1, (int)p2, (int)p3};
            i32x4 P1 = {(int)p4, (int)p5, (int)p6, (int)p7};
            *(i32x4*)&hLb[prow][pcol] = P0;
            *(i32x4*)&hLb[prow][pcol + 8] = P1;
        }
        // x-MFMAs before S1 (a1f drained by poll's vmcnt(0))
        f32x4 acc0 = {0.f, 0.f, 0.f, 0.f}, acc1 = {0.f, 0.f, 0.f, 0.f};
        f32x4 acc2 = {0.f, 0.f, 0.f, 0.f};
#pragma unroll
        for (int kt = 0; kt < 8; ++kt) {
            bf16x8 a = __builtin_bit_cast(bf16x8, a1f[kt]);
            acc0 = __builtin_amdgcn_mfma_f32_16x16x32_bf16(a, B1[0][kt], acc0, 0, 0, 0);
            acc1 = __builtin_amdgcn_mfma_f32_16x16x32_bf16(a, B1[1][kt], acc1, 0, 0, 0);
        }
        if (wave == 1) {
#pragma unroll
            for (int kt = 0; kt < 8; ++kt) {
                bf16x8 a = __builtin_bit_cast(bf16x8, a1f[kt]);
                acc2 = __builtin_amdgcn_mfma_f32_16x16x32_bf16(a, B1m[kt], acc2, 0, 0, 0);
            }
        }
        __syncthreads();   // S1: h tile staged

        // ---- phase D: h-MFMAs from LDS ----
#pragma unroll
        for (int kt = 0; kt < 16; ++kt) {
            bf16x8 a = *(const bf16x8*)&hLb[arow][kt * 32 + koct];
            acc0 = __builtin_amdgcn_mfma_f32_16x16x32_bf16(a, B2[0][kt], acc0, 0, 0, 0);
            acc1 = __builtin_amdgcn_mfma_f32_16x16x32_bf16(a, B2[1][kt], acc1, 0, 0, 0);
        }

        // ---- phase E: epilogue (C/D: col=lane&15, row=(lane>>4)*4+i; rows 0..7 in lanes<32) ----
        if (lane < 32) {
#pragma unroll
            for (int nt = 0; nt < 2; ++nt) {
                int j = wave * 32 + nt * 16 + (lane & 15);
                f32x4 a = nt ? acc1 : acc0;
#pragma unroll
                for (int i = 0; i < 4; ++i) {
                    int b = ((lane >> 4) << 2) + i;
                    float z = clip10(a[i] + biasv[nt]);
                    if (j < 64) {
                        int g = j >> 4;
                        g_lds[g][b][j & 15] = (g == 3) ? tanh_fast(z) : sigm_fast(z);
                    } else {
                        e_lds[b][j - 64] = z;
                    }
                }
            }
            if (wave == 1) {
#pragma unroll
                for (int i = 0; i < 4; ++i)
                    zm_lds[((lane >> 4) << 2) + i][lane & 15] = acc2[i];
            }
        }
        __syncthreads();   // S2: gates/e/zm ready

        // ---- phase F: pointwise + tagged-h release (waves 1,2) ----
        if (is_pw) {
            // max-free softmax numerators (|e|<=10 -> exp safe in fp32)
            const int base = pu * 4;
            const int k0 = t - 1 - base;
            float wv0 = __expf(e_lds[pb][(unsigned)(k0) & 63]);
            float wv1 = __expf(e_lds[pb][(unsigned)(k0 - 1) & 63]);
            float wv2 = __expf(e_lds[pb][(unsigned)(k0 - 2) & 63]);
            float wv3 = __expf(e_lds[pb][(unsigned)(k0 - 3) & 63]);
            float ssum = (wv0 + wv1) + (wv2 + wv3);
#pragma unroll
            for (int d = 1; d < 16; d <<= 1) ssum += __shfl_xor(ssum, d);
            float4 wq = {wv0, wv1, wv2, wv3};
            *(float4*)&w_lds[pb][base] = wq;
            asm volatile("" ::: "memory");   // keep ds_write before ds_reads
            float attn = 0.f;
            const float4* wr = (const float4*)&w_lds[pb][0];
            const float4* mr = (const float4*)&memF[pb * MEMF_PB + pu * MEMF_ROW];
#pragma unroll
            for (int p4i = 0; p4i < 16; ++p4i) {
                float4 w4 = wr[p4i], m4 = mr[p4i];
                attn = fmaf(w4.x, m4.x, attn);
                attn = fmaf(w4.y, m4.y, attn);
                attn = fmaf(w4.z, m4.z, attn);
                attn = fmaf(w4.w, m4.w, attn);
            }
            attn /= ssum;
            float ig = g_lds[0][pb][pu];
            float fg = g_lds[1][pb][pu];
            float og = g_lds[2][pb][pu];
            float ct = g_lds[3][pb][pu];
            float c = fg * (attn + zm_lds[pb][pu]) + ig * ct;
            float h = og * tanh_fast(c);
            // tagged-h release: single store, NO drain, NO flag
            unsigned tagval = (((unsigned)(t + 1)) << 16) | (unsigned)f2b(h);
            const unsigned* haddr = Hbuf32 + (wpar << 15) + (b0 + pb) * 512 + u0 + pu;
            asm volatile("global_store_dword %0, %1, off sc0 sc1"
                         :: "v"(haddr), "v"(tagval) : "memory");
            // off-critical-path writes (drained by next poll's vmcnt(0))
            memF[pb * MEMF_PB + pu * MEMF_ROW + (t & 63)] = c;
            out[((b0 + pb) * T_SZ + t) * U_SZ + u0 + pu] = h;
        }
        // no end barrier: S2(t) separates D(t) hLb readers from C(t+1) writers;
        // F(t) g/e/zm readers precede S1(t+1) which precedes E(t+1) writers.
        // memF/w_lds rows are wave-private.
    }
}

// ---------- launch ----------
extern "C" void kernel_launch(void* const* d_in, const int* in_sizes, int n_in,
                              void* d_out, int out_size, void* d_ws, size_t ws_size,
                              hipStream_t stream) {
    const float* x  = (const float*)d_in[0];
    const float* Wi = (const float*)d_in[1];
    const float* Ui = (const float*)d_in[2];
    const float* bi = (const float*)d_in[3];
    const float* Wf = (const float*)d_in[4];
    const float* Uf = (const float*)d_in[5];
    const float* bf = (const float*)d_in[6];
    const float* Wo = (const float*)d_in[7];
    const float* Uo = (const float*)d_in[8];
    const float* bo = (const float*)d_in[9];
    const float* Wc = (const float*)d_in[10];
    const float* Uc = (const float*)d_in[11];
    const float* bc = (const float*)d_in[12];
    const float* Wm = (const float*)d_in[13];
    const float* We = (const float*)d_in[14];
    const float* Ue = (const float*)d_in[15];
    const float* be = (const float*)d_in[16];

    char* ws = (char*)d_ws;
    const size_t off_xb    = 0;
    const size_t off_uslt  = off_xb + (size_t)B_SZ * T_SZ * D_SZ * 2;   // 16,777,216
    const size_t off_wslt  = off_uslt + (size_t)2112 * 512 * 2;         // +2,162,688
    const size_t off_hbuf  = off_wslt + (size_t)2624 * 256 * 2;         // +1,343,488
    ushortT* xb       = (ushortT*)(ws + off_xb);
    ushortT* UslT     = (ushortT*)(ws + off_uslt);
    ushortT* WslT     = (ushortT*)(ws + off_wslt);
    unsigned* Hbuf32  = (unsigned*)(ws + off_hbuf);   // 2*64*512*4 = 262,144 B
    float* out = (float*)d_out;

    // zero tagged-h double buffer (tags -> 0) — re-zeroed every replay
    (void)hipMemsetAsync(ws + off_hbuf, 0, 262144, stream);

    prep_xb_k<<<2048, 256, 0, stream>>>(x, xb);
    prep_uw_k<<<2048, 256, 0, stream>>>(Ui, Uf, Uo, Uc, Ue, Wi, Wf, Wo, Wc, We, Wm,
                                        UslT, WslT);

    xlstm_rec<<<dim3(256), dim3(256), 0, stream>>>(
        xb, UslT, WslT, bi, bf, bo, bc, be, Hbuf32, out);
}

// Round 13
// 2102.400 us; speedup vs baseline: 1.1016x; 1.1016x over previous
//
#include <hip/hip_runtime.h>
#include <hip/hip_bf16.h>

typedef unsigned short ushortT;
typedef __attribute__((ext_vector_type(8))) short bf16x8;
typedef __attribute__((ext_vector_type(4))) float f32x4;
typedef __attribute__((ext_vector_type(4))) int i32x4;

#define B_SZ 64
#define T_SZ 512
#define D_SZ 256
#define U_SZ 512
#define M_SZ 64

// ---------- helpers ----------
__device__ __forceinline__ ushortT f2b(float f) {
    __hip_bfloat16 h = __float2bfloat16(f);
    union { __hip_bfloat16 h; ushortT u; } c; c.h = h; return c.u;
}
__device__ __forceinline__ float clip10(float v) {
    return fminf(fmaxf(v, -10.f), 10.f);
}
__device__ __forceinline__ float tanh_fast(float z) {
    float e = __expf(2.f * z);
    return 1.f - 2.f / (e + 1.f);   // inf-safe
}
__device__ __forceinline__ float sigm_fast(float z) {
    return 1.f / (1.f + __expf(-z));
}

// ---------- prep: x -> clipped bf16 ----------
__global__ void prep_xb_k(const float* __restrict__ x, ushortT* __restrict__ xb) {
    const int n4 = (B_SZ * T_SZ * D_SZ) / 4;
    for (int i = blockIdx.x * blockDim.x + threadIdx.x; i < n4; i += gridDim.x * blockDim.x) {
        float4 v = ((const float4*)x)[i];
        ushort4 o;
        o.x = f2b(clip10(v.x));
        o.y = f2b(clip10(v.y));
        o.z = f2b(clip10(v.z));
        o.w = f2b(clip10(v.w));
        ((ushort4*)xb)[i] = o;
    }
}

// ---------- prep: U^T and W^T bf16 (transposed, col-major rows) ----------
// UslT cols: 0..2047 gate U cols, 2048..2111 Ue cols.
// WslT cols: 0..2047 gate W cols, 2048..2111 We cols, 2112..2623 Wm cols.
__global__ void prep_uw_k(const float* __restrict__ Ui, const float* __restrict__ Uf,
                          const float* __restrict__ Uo, const float* __restrict__ Uc,
                          const float* __restrict__ Ue,
                          const float* __restrict__ Wi, const float* __restrict__ Wf,
                          const float* __restrict__ Wo, const float* __restrict__ Wc,
                          const float* __restrict__ We, const float* __restrict__ Wm,
                          ushortT* __restrict__ UslT, ushortT* __restrict__ WslT) {
    const int NU = 2112 * 512;
    const int NW = 2624 * 256;
    for (int i = blockIdx.x * blockDim.x + threadIdx.x; i < NU + NW; i += gridDim.x * blockDim.x) {
        if (i < NU) {
            int c = i >> 9, k = i & 511;
            float v;
            if (c < 2048) {
                int g = c >> 9, u = c & 511;
                const float* U = (g == 0) ? Ui : (g == 1) ? Uf : (g == 2) ? Uo : Uc;
                v = U[k * 512 + u];
            } else {
                v = Ue[k * 64 + (c - 2048)];
            }
            UslT[i] = f2b(v);
        } else {
            int j = i - NU;
            int c = j >> 8, k = j & 255;
            float v;
            if (c < 2048) {
                int g = c >> 9, u = c & 511;
                const float* W = (g == 0) ? Wi : (g == 1) ? Wf : (g == 2) ? Wo : Wc;
                v = W[k * 512 + u];
            } else if (c < 2112) {
                v = We[k * 64 + (c - 2048)];
            } else {
                v = Wm[k * 512 + (c - 2112)];
            }
            WslT[j] = f2b(v);
        }
    }
}

#define MEMF_PB 1096   // floats per batch block (16 rows x 68 + 8 skew)
#define MEMF_ROW 68

// ---------- persistent recurrent kernel ----------
// Structure = R12 (proven 2316us) with ONE concept changed: CENTRALIZED poll.
// Each producer pw-wave writes its 4 granules with one store instruction, so
// one granule per producer wave serves as a sentinel (64 sentinels/group).
// Only wave 0 polls (64 lanes <-> 64 lines; 16x lower chip-wide poll rate);
// S0 barrier; then all waves bulk-read + RE-VALIDATE every tag (retry loop
// handles any cross-granule visibility skew — correctness never assumes
// same-instruction ordering). No counted vmcnt anywhere. G16-safe (LLC sc0 sc1).
__global__ __launch_bounds__(256, 1) void xlstm_rec(
    const ushortT* __restrict__ xb,    // [B*T][256] bf16 (clipped)
    const ushortT* __restrict__ UslT,  // [2112][512] bf16
    const ushortT* __restrict__ WslT,  // [2624][256] bf16
    const float* __restrict__ bi_p, const float* __restrict__ bf_p,
    const float* __restrict__ bo_p, const float* __restrict__ bc_p,
    const float* __restrict__ be_p,
    unsigned* __restrict__ Hbuf32,     // [2][64][512] u32 tagged h
    float* __restrict__ out)           // [64][512][512] fp32
{
    const int bid = blockIdx.x, tid = threadIdx.x;
    const int grp = bid & 7, rank = bid >> 3;
    const int wave = tid >> 6, lane = tid & 63;
    const int b0 = grp << 3;     // batch base
    const int u0 = rank << 4;    // unit base

    __shared__ float memF[8 * MEMF_PB];     // c ring: [pb][pu][slot(64)+pad] (thread-private rows)
    __shared__ float g_lds[4][8][16];       // i,f,o,ctilde
    __shared__ float e_lds[8][68];          // raw clipped e-logits (logical idx)
    __shared__ float w_lds[8][72];          // softmax numerators (physical slot)
    __shared__ float zm_lds[8][16];         // x_t @ Wm slice
    __shared__ ushortT hLb[8][520];         // h tile bf16, padded stride (1040B)

    for (int i = tid; i < 8 * MEMF_PB; i += 256) memF[i] = 0.f;

    // ---- register-resident weight B-fragments ----
    int cols[2];
    float biasv[2];
#pragma unroll
    for (int nt = 0; nt < 2; ++nt) {
        int j = wave * 32 + nt * 16 + (lane & 15);
        if (j < 64) {
            int g = j >> 4, u = u0 + (j & 15);
            cols[nt] = g * 512 + u;
            biasv[nt] = (g == 0) ? bi_p[u] : (g == 1) ? bf_p[u] : (g == 2) ? bo_p[u] : bc_p[u];
        } else {
            cols[nt] = 2048 + (j - 64);
            biasv[nt] = be_p[j - 64];
        }
    }
    const int koct = (lane >> 4) * 8;
    bf16x8 B1[2][8], B2[2][16], B1m[8];
#pragma unroll
    for (int nt = 0; nt < 2; ++nt) {
        const ushortT* bw = WslT + cols[nt] * 256;
#pragma unroll
        for (int kt = 0; kt < 8; ++kt)
            B1[nt][kt] = *(const bf16x8*)(bw + kt * 32 + koct);
        const ushortT* bu = UslT + cols[nt] * 512;
#pragma unroll
        for (int kt = 0; kt < 16; ++kt)
            B2[nt][kt] = *(const bf16x8*)(bu + kt * 32 + koct);
    }
    if (wave == 1) {   // Wm fragment (zm = x@Wm via MFMA)
        const ushortT* bm = WslT + (2112 + u0 + (lane & 15)) * 256;
#pragma unroll
        for (int kt = 0; kt < 8; ++kt)
            B1m[kt] = *(const bf16x8*)(bm + kt * 32 + koct);
    }

    const int arow = lane & 7;                 // MFMA A-operand batch row
    const bool is_pw = (tid >= 64 && tid < 192);
    const int pb = (tid - 64) >> 4;
    const int pu = (tid - 64) & 15;
    // bulk tagged-h fetch: wave w owns rows 2w (lanes<32), 2w+1 (lanes>=32)
    const int prow = 2 * wave + (lane >> 5);
    const int pcol = (lane & 31) * 16;         // 16 u32 units per lane (one 64B line)
    // wave0 sentinel map: lane -> producer wave (rank=lane&31, pwwave=lane>>5)
    // sentinel granule = (row 4*(lane>>5), col rank), word 0
    const int srow = (lane >> 5) * 4;
    const int scol = (lane & 31) * 16;

    __syncthreads();

    for (int t = 0; t < T_SZ; ++t) {
        const int par = t & 1, wpar = (t + 1) & 1;

        // ---- phase A: issue a1f x-fragment loads ----
        i32x4 a1f[8];
        {
            const ushortT* xrow = xb + ((b0 + arow) * T_SZ + t) * D_SZ + koct;
#pragma unroll
            for (int kt = 0; kt < 8; ++kt)
                asm volatile("global_load_dwordx4 %0, %1, off"
                             : "=v"(a1f[kt]) : "v"(xrow + kt * 32));
        }

        const unsigned T16 = ((unsigned)t) << 16;
        f32x4 acc0 = {0.f, 0.f, 0.f, 0.f}, acc1 = {0.f, 0.f, 0.f, 0.f};
        f32x4 acc2 = {0.f, 0.f, 0.f, 0.f};

        // ---- phase B0: wave0 polls 64 producer sentinels; others x-MFMA ----
        if (wave == 0) {
            const unsigned* sp = Hbuf32 + (par << 15) + (b0 + srow) * 512 + scol;
            while (true) {
                unsigned s;
                asm volatile("global_load_dword %0, %1, off sc0 sc1\n\t"
                             "s_waitcnt vmcnt(0)"
                             : "=v"(s) : "v"(sp) : "memory");
                if (__all(((s ^ T16) & 0xFFFF0000u) == 0u)) break;
            }
        } else {
            // drain a1f (+ own F(t-1) store acks) then x-MFMA, hidden under poll
            asm volatile("s_waitcnt vmcnt(0)"
                         : "+v"(a1f[0]), "+v"(a1f[1]), "+v"(a1f[2]), "+v"(a1f[3]),
                           "+v"(a1f[4]), "+v"(a1f[5]), "+v"(a1f[6]), "+v"(a1f[7])
                         :: "memory");
            __builtin_amdgcn_sched_barrier(0);
#pragma unroll
            for (int kt = 0; kt < 8; ++kt) {
                bf16x8 a = __builtin_bit_cast(bf16x8, a1f[kt]);
                acc0 = __builtin_amdgcn_mfma_f32_16x16x32_bf16(a, B1[0][kt], acc0, 0, 0, 0);
                acc1 = __builtin_amdgcn_mfma_f32_16x16x32_bf16(a, B1[1][kt], acc1, 0, 0, 0);
            }
            if (wave == 1) {
#pragma unroll
                for (int kt = 0; kt < 8; ++kt) {
                    bf16x8 a = __builtin_bit_cast(bf16x8, a1f[kt]);
                    acc2 = __builtin_amdgcn_mfma_f32_16x16x32_bf16(a, B1m[kt], acc2, 0, 0, 0);
                }
            }
        }
        __syncthreads();   // S0: all producer-wave stores for step t detected

        // ---- phase B2: bulk read own 64B line + full tag validation ----
        const unsigned* hsrc = Hbuf32 + (par << 15) + (b0 + prow) * 512 + pcol;
        i32x4 g0, g1, g2, g3;
        {
            // first issue; wave0's x-MFMA hides under this load's latency
            asm volatile("global_load_dwordx4 %0, %4, off sc0 sc1\n\t"
                         "global_load_dwordx4 %1, %4, off offset:16 sc0 sc1\n\t"
                         "global_load_dwordx4 %2, %4, off offset:32 sc0 sc1\n\t"
                         "global_load_dwordx4 %3, %4, off offset:48 sc0 sc1"
                         : "=v"(g0), "=v"(g1), "=v"(g2), "=v"(g3)
                         : "v"(hsrc) : "memory");
        }
        if (wave == 0) {
            // a1f already drained by poll's vmcnt(0)
#pragma unroll
            for (int kt = 0; kt < 8; ++kt) {
                bf16x8 a = __builtin_bit_cast(bf16x8, a1f[kt]);
                acc0 = __builtin_amdgcn_mfma_f32_16x16x32_bf16(a, B1[0][kt], acc0, 0, 0, 0);
                acc1 = __builtin_amdgcn_mfma_f32_16x16x32_bf16(a, B1[1][kt], acc1, 0, 0, 0);
            }
        }
        while (true) {
            asm volatile("s_waitcnt vmcnt(0)"
                         : "+v"(g0), "+v"(g1), "+v"(g2), "+v"(g3) :: "memory");
            unsigned d = (((unsigned)g0[0] ^ T16) | ((unsigned)g0[1] ^ T16)) |
                         (((unsigned)g0[2] ^ T16) | ((unsigned)g0[3] ^ T16));
            d |= (((unsigned)g1[0] ^ T16) | ((unsigned)g1[1] ^ T16)) |
                 (((unsigned)g1[2] ^ T16) | ((unsigned)g1[3] ^ T16));
            d |= (((unsigned)g2[0] ^ T16) | ((unsigned)g2[1] ^ T16)) |
                 (((unsigned)g2[2] ^ T16) | ((unsigned)g2[3] ^ T16));
            d |= (((unsigned)g3[0] ^ T16) | ((unsigned)g3[1] ^ T16)) |
                 (((unsigned)g3[2] ^ T16) | ((unsigned)g3[3] ^ T16));
            if (__all((d & 0xFFFF0000u) == 0u)) break;
            __builtin_amdgcn_s_sleep(1);   // rare: visibility skew within a store instr
            asm volatile("global_load_dwordx4 %0, %4, off sc0 sc1\n\t"
                         "global_load_dwordx4 %1, %4, off offset:16 sc0 sc1\n\t"
                         "global_load_dwordx4 %2, %4, off offset:32 sc0 sc1\n\t"
                         "global_load_dwordx4 %3, %4, off offset:48 sc0 sc1"
                         : "=v"(g0), "=v"(g1), "=v"(g2), "=v"(g3)
                         : "v"(hsrc) : "memory");
        }
        __builtin_amdgcn_sched_barrier(0);

        // ---- phase C: strip tags, pack bf16 pairs, stage into LDS ----
        {
            unsigned p0 = ((unsigned)g0[0] & 0xFFFFu) | ((unsigned)g0[1] << 16);
            unsigned p1 = ((unsigned)g0[2] & 0xFFFFu) | ((unsigned)g0[3] << 16);
            unsigned p2 = ((unsigned)g1[0] & 0xFFFFu) | ((unsigned)g1[1] << 16);
            unsigned p3 = ((unsigned)g1[2] & 0xFFFFu) | ((unsigned)g1[3] << 16);
            unsigned p4 = ((unsigned)g2[0] & 0xFFFFu) | ((unsigned)g2[1] << 16);
            unsigned p5 = ((unsigned)g2[2] & 0xFFFFu) | ((unsigned)g2[3] << 16);
            unsigned p6 = ((unsigned)g3[0] & 0xFFFFu) | ((unsigned)g3[1] << 16);
            unsigned p7 = ((unsigned)g3[2] & 0xFFFFu) | ((unsigned)g3[3] << 16);
            i32x4 P0 = {(int)p0, (int)p1, (int)p2, (int)p3};
            i32x4 P1 = {(int)p4, (int)p5, (int)p6, (int)p7};
            *(i32x4*)&hLb[prow][pcol] = P0;
            *(i32x4*)&hLb[prow][pcol + 8] = P1;
        }
        __syncthreads();   // S1: h tile staged

        // ---- phase D: h-MFMAs from LDS ----
#pragma unroll
        for (int kt = 0; kt < 16; ++kt) {
            bf16x8 a = *(const bf16x8*)&hLb[arow][kt * 32 + koct];
            acc0 = __builtin_amdgcn_mfma_f32_16x16x32_bf16(a, B2[0][kt], acc0, 0, 0, 0);
            acc1 = __builtin_amdgcn_mfma_f32_16x16x32_bf16(a, B2[1][kt], acc1, 0, 0, 0);
        }

        // ---- phase E: epilogue (C/D: col=lane&15, row=(lane>>4)*4+i; rows 0..7 in lanes<32) ----
        if (lane < 32) {
#pragma unroll
            for (int nt = 0; nt < 2; ++nt) {
                int j = wave * 32 + nt * 16 + (lane & 15);
                f32x4 a = nt ? acc1 : acc0;
#pragma unroll
                for (int i = 0; i < 4; ++i) {
                    int b = ((lane >> 4) << 2) + i;
                    float z = clip10(a[i] + biasv[nt]);
                    if (j < 64) {
                        int g = j >> 4;
                        g_lds[g][b][j & 15] = (g == 3) ? tanh_fast(z) : sigm_fast(z);
                    } else {
                        e_lds[b][j - 64] = z;
                    }
                }
            }
            if (wave == 1) {
#pragma unroll
                for (int i = 0; i < 4; ++i)
                    zm_lds[((lane >> 4) << 2) + i][lane & 15] = acc2[i];
            }
        }
        __syncthreads();   // S2: gates/e/zm ready

        // ---- phase F: pointwise + tagged-h release (waves 1,2) ----
        if (is_pw) {
            // max-free softmax numerators (|e|<=10 -> exp safe in fp32)
            const int base = pu * 4;
            const int k0 = t - 1 - base;
            float wv0 = __expf(e_lds[pb][(unsigned)(k0) & 63]);
            float wv1 = __expf(e_lds[pb][(unsigned)(k0 - 1) & 63]);
            float wv2 = __expf(e_lds[pb][(unsigned)(k0 - 2) & 63]);
            float wv3 = __expf(e_lds[pb][(unsigned)(k0 - 3) & 63]);
            float ssum = (wv0 + wv1) + (wv2 + wv3);
#pragma unroll
            for (int d = 1; d < 16; d <<= 1) ssum += __shfl_xor(ssum, d);
            float4 wq = {wv0, wv1, wv2, wv3};
            *(float4*)&w_lds[pb][base] = wq;
            asm volatile("" ::: "memory");   // keep ds_write before ds_reads
            float attn = 0.f;
            const float4* wr = (const float4*)&w_lds[pb][0];
            const float4* mr = (const float4*)&memF[pb * MEMF_PB + pu * MEMF_ROW];
#pragma unroll
            for (int p4i = 0; p4i < 16; ++p4i) {
                float4 w4 = wr[p4i], m4 = mr[p4i];
                attn = fmaf(w4.x, m4.x, attn);
                attn = fmaf(w4.y, m4.y, attn);
                attn = fmaf(w4.z, m4.z, attn);
                attn = fmaf(w4.w, m4.w, attn);
            }
            attn /= ssum;
            float ig = g_lds[0][pb][pu];
            float fg = g_lds[1][pb][pu];
            float og = g_lds[2][pb][pu];
            float ct = g_lds[3][pb][pu];
            float c = fg * (attn + zm_lds[pb][pu]) + ig * ct;
            float h = og * tanh_fast(c);
            // tagged-h release: single store, NO drain, NO flag
            unsigned tagval = (((unsigned)(t + 1)) << 16) | (unsigned)f2b(h);
            const unsigned* haddr = Hbuf32 + (wpar << 15) + (b0 + pb) * 512 + u0 + pu;
            asm volatile("global_store_dword %0, %1, off sc0 sc1"
                         :: "v"(haddr), "v"(tagval) : "memory");
            // off-critical-path writes (drained by next step's vmcnt(0))
            memF[pb * MEMF_PB + pu * MEMF_ROW + (t & 63)] = c;
            out[((b0 + pb) * T_SZ + t) * U_SZ + u0 + pu] = h;
        }
        // no end barrier needed: S0(t+1) precedes all hLb writes at t+1, and a
        // wave reaching S0(t+1) has finished F(t); all-waves-at-S1(t+1) implies
        // all F(t) complete before E(t+1) writes g/e/zm. memF/w_lds wave-private.
    }
}

// ---------- launch ----------
extern "C" void kernel_launch(void* const* d_in, const int* in_sizes, int n_in,
                              void* d_out, int out_size, void* d_ws, size_t ws_size,
                              hipStream_t stream) {
    const float* x  = (const float*)d_in[0];
    const float* Wi = (const float*)d_in[1];
    const float* Ui = (const float*)d_in[2];
    const float* bi = (const float*)d_in[3];
    const float* Wf = (const float*)d_in[4];
    const float* Uf = (const float*)d_in[5];
    const float* bf = (const float*)d_in[6];
    const float* Wo = (const float*)d_in[7];
    const float* Uo = (const float*)d_in[8];
    const float* bo = (const float*)d_in[9];
    const float* Wc = (const float*)d_in[10];
    const float* Uc = (const float*)d_in[11];
    const float* bc = (const float*)d_in[12];
    const float* Wm = (const float*)d_in[13];
    const float* We = (const float*)d_in[14];
    const float* Ue = (const float*)d_in[15];
    const float* be = (const float*)d_in[16];

    char* ws = (char*)d_ws;
    const size_t off_xb    = 0;
    const size_t off_uslt  = off_xb + (size_t)B_SZ * T_SZ * D_SZ * 2;   // 16,777,216
    const size_t off_wslt  = off_uslt + (size_t)2112 * 512 * 2;         // +2,162,688
    const size_t off_hbuf  = off_wslt + (size_t)2624 * 256 * 2;         // +1,343,488
    ushortT* xb       = (ushortT*)(ws + off_xb);
    ushortT* UslT     = (ushortT*)(ws + off_uslt);
    ushortT* WslT     = (ushortT*)(ws + off_wslt);
    unsigned* Hbuf32  = (unsigned*)(ws + off_hbuf);   // 2*64*512*4 = 262,144 B
    float* out = (float*)d_out;

    // zero tagged-h double buffer (tags -> 0) — re-zeroed every replay
    (void)hipMemsetAsync(ws + off_hbuf, 0, 262144, stream);

    prep_xb_k<<<2048, 256, 0, stream>>>(x, xb);
    prep_uw_k<<<2048, 256, 0, stream>>>(Ui, Uf, Uo, Uc, Ue, Wi, Wf, Wo, Wc, We, Wm,
                                        UslT, WslT);

    xlstm_rec<<<dim3(256), dim3(256), 0, stream>>>(
        xb, UslT, WslT, bi, bf, bo, bc, be, Hbuf32, out);
}

// Round 14
// 2034.085 us; speedup vs baseline: 1.1386x; 1.0336x over previous
//
#include <hip/hip_runtime.h>
#include <hip/hip_bf16.h>

typedef unsigned short ushortT;
typedef __attribute__((ext_vector_type(8))) short bf16x8;
typedef __attribute__((ext_vector_type(4))) float f32x4;
typedef __attribute__((ext_vector_type(4))) int i32x4;

#define B_SZ 64
#define T_SZ 512
#define D_SZ 256
#define U_SZ 512
#define M_SZ 64

// ---------- helpers ----------
__device__ __forceinline__ ushortT f2b(float f) {
    __hip_bfloat16 h = __float2bfloat16(f);
    union { __hip_bfloat16 h; ushortT u; } c; c.h = h; return c.u;
}
__device__ __forceinline__ float clip10(float v) {
    return fminf(fmaxf(v, -10.f), 10.f);
}
__device__ __forceinline__ float tanh_fast(float z) {
    float e = __expf(2.f * z);
    return 1.f - 2.f / (e + 1.f);   // inf-safe
}
__device__ __forceinline__ float sigm_fast(float z) {
    return 1.f / (1.f + __expf(-z));
}

// ---------- prep: x -> clipped bf16 ----------
__global__ void prep_xb_k(const float* __restrict__ x, ushortT* __restrict__ xb) {
    const int n4 = (B_SZ * T_SZ * D_SZ) / 4;
    for (int i = blockIdx.x * blockDim.x + threadIdx.x; i < n4; i += gridDim.x * blockDim.x) {
        float4 v = ((const float4*)x)[i];
        ushort4 o;
        o.x = f2b(clip10(v.x));
        o.y = f2b(clip10(v.y));
        o.z = f2b(clip10(v.z));
        o.w = f2b(clip10(v.w));
        ((ushort4*)xb)[i] = o;
    }
}

// ---------- prep: U^T and W^T bf16 (transposed, col-major rows) ----------
// UslT cols: 0..2047 gate U cols, 2048..2111 Ue cols.
// WslT cols: 0..2047 gate W cols, 2048..2111 We cols, 2112..2623 Wm cols.
__global__ void prep_uw_k(const float* __restrict__ Ui, const float* __restrict__ Uf,
                          const float* __restrict__ Uo, const float* __restrict__ Uc,
                          const float* __restrict__ Ue,
                          const float* __restrict__ Wi, const float* __restrict__ Wf,
                          const float* __restrict__ Wo, const float* __restrict__ Wc,
                          const float* __restrict__ We, const float* __restrict__ Wm,
                          ushortT* __restrict__ UslT, ushortT* __restrict__ WslT) {
    const int NU = 2112 * 512;
    const int NW = 2624 * 256;
    for (int i = blockIdx.x * blockDim.x + threadIdx.x; i < NU + NW; i += gridDim.x * blockDim.x) {
        if (i < NU) {
            int c = i >> 9, k = i & 511;
            float v;
            if (c < 2048) {
                int g = c >> 9, u = c & 511;
                const float* U = (g == 0) ? Ui : (g == 1) ? Uf : (g == 2) ? Uo : Uc;
                v = U[k * 512 + u];
            } else {
                v = Ue[k * 64 + (c - 2048)];
            }
            UslT[i] = f2b(v);
        } else {
            int j = i - NU;
            int c = j >> 8, k = j & 255;
            float v;
            if (c < 2048) {
                int g = c >> 9, u = c & 511;
                const float* W = (g == 0) ? Wi : (g == 1) ? Wf : (g == 2) ? Wo : Wc;
                v = W[k * 512 + u];
            } else if (c < 2112) {
                v = We[k * 64 + (c - 2048)];
            } else {
                v = Wm[k * 512 + (c - 2112)];
            }
            WslT[j] = f2b(v);
        }
    }
}

#define MEMF_PB 1096   // floats per batch block (16 rows x 68 + 8 skew)
#define MEMF_ROW 68

// ---------- persistent recurrent kernel ----------
// Structure = R13 (proven 2102us) with ONE concept added: DUAL-PATH h exchange.
// Producers store tagged h TWICE: mirror copy sc0 (XCD-L2, fast if the group
// is co-resident on one XCD) then authoritative copy sc0 sc1 (LLC, always
// works). Wave0 polls mirror sentinels 3/4 iters, LLC sentinel every 4th
// (guaranteed detection). Bulk read tries mirror ONCE; any stale tag -> LLC
// retry loop (guaranteed). Every word self-validates (tag<<16|bf16), so the
// fast path is advisory only — no hang modes, placement-independent (G16).
__global__ __launch_bounds__(256, 1) void xlstm_rec(
    const ushortT* __restrict__ xb,    // [B*T][256] bf16 (clipped)
    const ushortT* __restrict__ UslT,  // [2112][512] bf16
    const ushortT* __restrict__ WslT,  // [2624][256] bf16
    const float* __restrict__ bi_p, const float* __restrict__ bf_p,
    const float* __restrict__ bo_p, const float* __restrict__ bc_p,
    const float* __restrict__ be_p,
    unsigned* __restrict__ Hbuf32,     // [2][64][512] u32 tagged h (LLC copy)
    unsigned* __restrict__ Hmir,       // [2][64][512] u32 tagged h (L2 mirror)
    float* __restrict__ out)           // [64][512][512] fp32
{
    const int bid = blockIdx.x, tid = threadIdx.x;
    const int grp = bid & 7, rank = bid >> 3;
    const int wave = tid >> 6, lane = tid & 63;
    const int b0 = grp << 3;     // batch base
    const int u0 = rank << 4;    // unit base

    __shared__ float memF[8 * MEMF_PB];     // c ring: [pb][pu][slot(64)+pad] (thread-private rows)
    __shared__ float g_lds[4][8][16];       // i,f,o,ctilde
    __shared__ float e_lds[8][68];          // raw clipped e-logits (logical idx)
    __shared__ float w_lds[8][72];          // softmax numerators (physical slot)
    __shared__ float zm_lds[8][16];         // x_t @ Wm slice
    __shared__ ushortT hLb[8][520];         // h tile bf16, padded stride (1040B)

    for (int i = tid; i < 8 * MEMF_PB; i += 256) memF[i] = 0.f;

    // ---- register-resident weight B-fragments ----
    int cols[2];
    float biasv[2];
#pragma unroll
    for (int nt = 0; nt < 2; ++nt) {
        int j = wave * 32 + nt * 16 + (lane & 15);
        if (j < 64) {
            int g = j >> 4, u = u0 + (j & 15);
            cols[nt] = g * 512 + u;
            biasv[nt] = (g == 0) ? bi_p[u] : (g == 1) ? bf_p[u] : (g == 2) ? bo_p[u] : bc_p[u];
        } else {
            cols[nt] = 2048 + (j - 64);
            biasv[nt] = be_p[j - 64];
        }
    }
    const int koct = (lane >> 4) * 8;
    bf16x8 B1[2][8], B2[2][16], B1m[8];
#pragma unroll
    for (int nt = 0; nt < 2; ++nt) {
        const ushortT* bw = WslT + cols[nt] * 256;
#pragma unroll
        for (int kt = 0; kt < 8; ++kt)
            B1[nt][kt] = *(const bf16x8*)(bw + kt * 32 + koct);
        const ushortT* bu = UslT + cols[nt] * 512;
#pragma unroll
        for (int kt = 0; kt < 16; ++kt)
            B2[nt][kt] = *(const bf16x8*)(bu + kt * 32 + koct);
    }
    if (wave == 1) {   // Wm fragment (zm = x@Wm via MFMA)
        const ushortT* bm = WslT + (2112 + u0 + (lane & 15)) * 256;
#pragma unroll
        for (int kt = 0; kt < 8; ++kt)
            B1m[kt] = *(const bf16x8*)(bm + kt * 32 + koct);
    }

    const int arow = lane & 7;                 // MFMA A-operand batch row
    const bool is_pw = (tid >= 64 && tid < 192);
    const int pb = (tid - 64) >> 4;
    const int pu = (tid - 64) & 15;
    // bulk tagged-h fetch: wave w owns rows 2w (lanes<32), 2w+1 (lanes>=32)
    const int prow = 2 * wave + (lane >> 5);
    const int pcol = (lane & 31) * 16;         // 16 u32 units per lane (one 64B line)
    // wave0 sentinel map: sentinel granule = (row 4*(lane>>5), col lane&31), word 0
    const int srow = (lane >> 5) * 4;
    const int scol = (lane & 31) * 16;

    __syncthreads();

    for (int t = 0; t < T_SZ; ++t) {
        const int par = t & 1, wpar = (t + 1) & 1;

        // ---- phase A: issue a1f x-fragment loads ----
        i32x4 a1f[8];
        {
            const ushortT* xrow = xb + ((b0 + arow) * T_SZ + t) * D_SZ + koct;
#pragma unroll
            for (int kt = 0; kt < 8; ++kt)
                asm volatile("global_load_dwordx4 %0, %1, off"
                             : "=v"(a1f[kt]) : "v"(xrow + kt * 32));
        }

        const unsigned T16 = ((unsigned)t) << 16;
        f32x4 acc0 = {0.f, 0.f, 0.f, 0.f}, acc1 = {0.f, 0.f, 0.f, 0.f};
        f32x4 acc2 = {0.f, 0.f, 0.f, 0.f};

        // ---- phase B0: wave0 polls sentinels (mirror-biased); others x-MFMA ----
        if (wave == 0) {
            const unsigned* msp = Hmir + (par << 15) + (b0 + srow) * 512 + scol;
            const unsigned* lsp = Hbuf32 + (par << 15) + (b0 + srow) * 512 + scol;
            unsigned it = 0;
            bool sat = false;
            while (true) {
                unsigned s;
                if ((it & 3u) != 3u)
                    asm volatile("global_load_dword %0, %1, off sc0\n\ts_waitcnt vmcnt(0)"
                                 : "=v"(s) : "v"(msp) : "memory");
                else
                    asm volatile("global_load_dword %0, %1, off sc0 sc1\n\ts_waitcnt vmcnt(0)"
                                 : "=v"(s) : "v"(lsp) : "memory");
                sat = sat || (((s ^ T16) & 0xFFFF0000u) == 0u);
                if (__all(sat)) break;
                ++it;
            }
        } else {
            // drain a1f (+ own F(t-1) store acks) then x-MFMA, hidden under poll
            asm volatile("s_waitcnt vmcnt(0)"
                         : "+v"(a1f[0]), "+v"(a1f[1]), "+v"(a1f[2]), "+v"(a1f[3]),
                           "+v"(a1f[4]), "+v"(a1f[5]), "+v"(a1f[6]), "+v"(a1f[7])
                         :: "memory");
            __builtin_amdgcn_sched_barrier(0);
#pragma unroll
            for (int kt = 0; kt < 8; ++kt) {
                bf16x8 a = __builtin_bit_cast(bf16x8, a1f[kt]);
                acc0 = __builtin_amdgcn_mfma_f32_16x16x32_bf16(a, B1[0][kt], acc0, 0, 0, 0);
                acc1 = __builtin_amdgcn_mfma_f32_16x16x32_bf16(a, B1[1][kt], acc1, 0, 0, 0);
            }
            if (wave == 1) {
#pragma unroll
                for (int kt = 0; kt < 8; ++kt) {
                    bf16x8 a = __builtin_bit_cast(bf16x8, a1f[kt]);
                    acc2 = __builtin_amdgcn_mfma_f32_16x16x32_bf16(a, B1m[kt], acc2, 0, 0, 0);
                }
            }
        }
        __syncthreads();   // S0: all producer-wave stores for step t detected

        // ---- phase B2: bulk read own 64B line — mirror once, LLC fallback ----
        const unsigned* msrc = Hmir + (par << 15) + (b0 + prow) * 512 + pcol;
        const unsigned* hsrc = Hbuf32 + (par << 15) + (b0 + prow) * 512 + pcol;
        i32x4 g0, g1, g2, g3;
        asm volatile("global_load_dwordx4 %0, %4, off sc0\n\t"
                     "global_load_dwordx4 %1, %4, off offset:16 sc0\n\t"
                     "global_load_dwordx4 %2, %4, off offset:32 sc0\n\t"
                     "global_load_dwordx4 %3, %4, off offset:48 sc0"
                     : "=v"(g0), "=v"(g1), "=v"(g2), "=v"(g3)
                     : "v"(msrc) : "memory");
        if (wave == 0) {
            // a1f already drained by poll's vmcnt(0); x-MFMA under load latency
#pragma unroll
            for (int kt = 0; kt < 8; ++kt) {
                bf16x8 a = __builtin_bit_cast(bf16x8, a1f[kt]);
                acc0 = __builtin_amdgcn_mfma_f32_16x16x32_bf16(a, B1[0][kt], acc0, 0, 0, 0);
                acc1 = __builtin_amdgcn_mfma_f32_16x16x32_bf16(a, B1[1][kt], acc1, 0, 0, 0);
            }
        }
        {
            asm volatile("s_waitcnt vmcnt(0)"
                         : "+v"(g0), "+v"(g1), "+v"(g2), "+v"(g3) :: "memory");
            unsigned d = (((unsigned)g0[0] ^ T16) | ((unsigned)g0[1] ^ T16)) |
                         (((unsigned)g0[2] ^ T16) | ((unsigned)g0[3] ^ T16));
            d |= (((unsigned)g1[0] ^ T16) | ((unsigned)g1[1] ^ T16)) |
                 (((unsigned)g1[2] ^ T16) | ((unsigned)g1[3] ^ T16));
            d |= (((unsigned)g2[0] ^ T16) | ((unsigned)g2[1] ^ T16)) |
                 (((unsigned)g2[2] ^ T16) | ((unsigned)g2[3] ^ T16));
            d |= (((unsigned)g3[0] ^ T16) | ((unsigned)g3[1] ^ T16)) |
                 (((unsigned)g3[2] ^ T16) | ((unsigned)g3[3] ^ T16));
            bool ok = __all((d & 0xFFFF0000u) == 0u);
            while (!ok) {   // authoritative LLC path (guaranteed to converge)
                asm volatile("global_load_dwordx4 %0, %4, off sc0 sc1\n\t"
                             "global_load_dwordx4 %1, %4, off offset:16 sc0 sc1\n\t"
                             "global_load_dwordx4 %2, %4, off offset:32 sc0 sc1\n\t"
                             "global_load_dwordx4 %3, %4, off offset:48 sc0 sc1\n\t"
                             "s_waitcnt vmcnt(0)"
                             : "=v"(g0), "=v"(g1), "=v"(g2), "=v"(g3)
                             : "v"(hsrc) : "memory");
                unsigned d2 = (((unsigned)g0[0] ^ T16) | ((unsigned)g0[1] ^ T16)) |
                              (((unsigned)g0[2] ^ T16) | ((unsigned)g0[3] ^ T16));
                d2 |= (((unsigned)g1[0] ^ T16) | ((unsigned)g1[1] ^ T16)) |
                      (((unsigned)g1[2] ^ T16) | ((unsigned)g1[3] ^ T16));
                d2 |= (((unsigned)g2[0] ^ T16) | ((unsigned)g2[1] ^ T16)) |
                      (((unsigned)g2[2] ^ T16) | ((unsigned)g2[3] ^ T16));
                d2 |= (((unsigned)g3[0] ^ T16) | ((unsigned)g3[1] ^ T16)) |
                      (((unsigned)g3[2] ^ T16) | ((unsigned)g3[3] ^ T16));
                ok = __all((d2 & 0xFFFF0000u) == 0u);
            }
        }
        __builtin_amdgcn_sched_barrier(0);

        // ---- phase C: strip tags, pack bf16 pairs, stage into LDS ----
        {
            unsigned p0 = ((unsigned)g0[0] & 0xFFFFu) | ((unsigned)g0[1] << 16);
            unsigned p1 = ((unsigned)g0[2] & 0xFFFFu) | ((unsigned)g0[3] << 16);
            unsigned p2 = ((unsigned)g1[0] & 0xFFFFu) | ((unsigned)g1[1] << 16);
            unsigned p3 = ((unsigned)g1[2] & 0xFFFFu) | ((unsigned)g1[3] << 16);
            unsigned p4 = ((unsigned)g2[0] & 0xFFFFu) | ((unsigned)g2[1] << 16);
            unsigned p5 = ((unsigned)g2[2] & 0xFFFFu) | ((unsigned)g2[3] << 16);
            unsigned p6 = ((unsigned)g3[0] & 0xFFFFu) | ((unsigned)g3[1] << 16);
            unsigned p7 = ((unsigned)g3[2] & 0xFFFFu) | ((unsigned)g3[3] << 16);
            i32x4 P0 = {(int)p0, (int)p1, (int)p2, (int)p3};
            i32x4 P1 = {(int)p4, (int)p5, (int)p6, (int)p7};
            *(i32x4*)&hLb[prow][pcol] = P0;
            *(i32x4*)&hLb[prow][pcol + 8] = P1;
        }
        __syncthreads();   // S1: h tile staged

        // ---- phase D: h-MFMAs from LDS ----
#pragma unroll
        for (int kt = 0; kt < 16; ++kt) {
            bf16x8 a = *(const bf16x8*)&hLb[arow][kt * 32 + koct];
            acc0 = __builtin_amdgcn_mfma_f32_16x16x32_bf16(a, B2[0][kt], acc0, 0, 0, 0);
            acc1 = __builtin_amdgcn_mfma_f32_16x16x32_bf16(a, B2[1][kt], acc1, 0, 0, 0);
        }

        // ---- phase E: epilogue (C/D: col=lane&15, row=(lane>>4)*4+i; rows 0..7 in lanes<32) ----
        if (lane < 32) {
#pragma unroll
            for (int nt = 0; nt < 2; ++nt) {
                int j = wave * 32 + nt * 16 + (lane & 15);
                f32x4 a = nt ? acc1 : acc0;
#pragma unroll
                for (int i = 0; i < 4; ++i) {
                    int b = ((lane >> 4) << 2) + i;
                    float z = clip10(a[i] + biasv[nt]);
                    if (j < 64) {
                        int g = j >> 4;
                        g_lds[g][b][j & 15] = (g == 3) ? tanh_fast(z) : sigm_fast(z);
                    } else {
                        e_lds[b][j - 64] = z;
                    }
                }
            }
            if (wave == 1) {
#pragma unroll
                for (int i = 0; i < 4; ++i)
                    zm_lds[((lane >> 4) << 2) + i][lane & 15] = acc2[i];
            }
        }
        __syncthreads();   // S2: gates/e/zm ready

        // ---- phase F: pointwise + dual tagged-h release (waves 1,2) ----
        if (is_pw) {
            // max-free softmax numerators (|e|<=10 -> exp safe in fp32)
            const int base = pu * 4;
            const int k0 = t - 1 - base;
            float wv0 = __expf(e_lds[pb][(unsigned)(k0) & 63]);
            float wv1 = __expf(e_lds[pb][(unsigned)(k0 - 1) & 63]);
            float wv2 = __expf(e_lds[pb][(unsigned)(k0 - 2) & 63]);
            float wv3 = __expf(e_lds[pb][(unsigned)(k0 - 3) & 63]);
            float ssum = (wv0 + wv1) + (wv2 + wv3);
#pragma unroll
            for (int d = 1; d < 16; d <<= 1) ssum += __shfl_xor(ssum, d);
            float4 wq = {wv0, wv1, wv2, wv3};
            *(float4*)&w_lds[pb][base] = wq;
            asm volatile("" ::: "memory");   // keep ds_write before ds_reads
            float attn = 0.f;
            const float4* wr = (const float4*)&w_lds[pb][0];
            const float4* mr = (const float4*)&memF[pb * MEMF_PB + pu * MEMF_ROW];
#pragma unroll
            for (int p4i = 0; p4i < 16; ++p4i) {
                float4 w4 = wr[p4i], m4 = mr[p4i];
                attn = fmaf(w4.x, m4.x, attn);
                attn = fmaf(w4.y, m4.y, attn);
                attn = fmaf(w4.z, m4.z, attn);
                attn = fmaf(w4.w, m4.w, attn);
            }
            attn /= ssum;
            float ig = g_lds[0][pb][pu];
            float fg = g_lds[1][pb][pu];
            float og = g_lds[2][pb][pu];
            float ct = g_lds[3][pb][pu];
            float c = fg * (attn + zm_lds[pb][pu]) + ig * ct;
            float h = og * tanh_fast(c);
            // dual tagged-h release: mirror (L2) first, then authoritative LLC
            unsigned tagval = (((unsigned)(t + 1)) << 16) | (unsigned)f2b(h);
            const unsigned off = (unsigned)((wpar << 15) + (b0 + pb) * 512 + u0 + pu);
            asm volatile("global_store_dword %0, %1, off sc0"
                         :: "v"(Hmir + off), "v"(tagval) : "memory");
            asm volatile("global_store_dword %0, %1, off sc0 sc1"
                         :: "v"(Hbuf32 + off), "v"(tagval) : "memory");
            // off-critical-path writes (drained by next step's vmcnt(0))
            memF[pb * MEMF_PB + pu * MEMF_ROW + (t & 63)] = c;
            out[((b0 + pb) * T_SZ + t) * U_SZ + u0 + pu] = h;
        }
        // no end barrier needed: S0(t+1) precedes all hLb writes at t+1, and a
        // wave reaching S0(t+1) has finished F(t); all-waves-at-S1(t+1) implies
        // all F(t) complete before E(t+1) writes g/e/zm. memF/w_lds wave-private.
    }
}

// ---------- launch ----------
extern "C" void kernel_launch(void* const* d_in, const int* in_sizes, int n_in,
                              void* d_out, int out_size, void* d_ws, size_t ws_size,
                              hipStream_t stream) {
    const float* x  = (const float*)d_in[0];
    const float* Wi = (const float*)d_in[1];
    const float* Ui = (const float*)d_in[2];
    const float* bi = (const float*)d_in[3];
    const float* Wf = (const float*)d_in[4];
    const float* Uf = (const float*)d_in[5];
    const float* bf = (const float*)d_in[6];
    const float* Wo = (const float*)d_in[7];
    const float* Uo = (const float*)d_in[8];
    const float* bo = (const float*)d_in[9];
    const float* Wc = (const float*)d_in[10];
    const float* Uc = (const float*)d_in[11];
    const float* bc = (const float*)d_in[12];
    const float* Wm = (const float*)d_in[13];
    const float* We = (const float*)d_in[14];
    const float* Ue = (const float*)d_in[15];
    const float* be = (const float*)d_in[16];

    char* ws = (char*)d_ws;
    const size_t off_xb    = 0;
    const size_t off_uslt  = off_xb + (size_t)B_SZ * T_SZ * D_SZ * 2;   // 16,777,216
    const size_t off_wslt  = off_uslt + (size_t)2112 * 512 * 2;         // +2,162,688
    const size_t off_hbuf  = off_wslt + (size_t)2624 * 256 * 2;         // +1,343,488
    const size_t off_hmir  = off_hbuf + 262144;
    ushortT* xb       = (ushortT*)(ws + off_xb);
    ushortT* UslT     = (ushortT*)(ws + off_uslt);
    ushortT* WslT     = (ushortT*)(ws + off_wslt);
    unsigned* Hbuf32  = (unsigned*)(ws + off_hbuf);   // 2*64*512*4 = 262,144 B
    unsigned* Hmir    = (unsigned*)(ws + off_hmir);   // 262,144 B
    float* out = (float*)d_out;

    // zero both tagged-h double buffers (tags -> 0) — re-zeroed every replay
    (void)hipMemsetAsync(ws + off_hbuf, 0, 524288, stream);

    prep_xb_k<<<2048, 256, 0, stream>>>(x, xb);
    prep_uw_k<<<2048, 256, 0, stream>>>(Ui, Uf, Uo, Uc, Ue, Wi, Wf, Wo, Wc, We, Wm,
                                        UslT, WslT);

    xlstm_rec<<<dim3(256), dim3(256), 0, stream>>>(
        xb, UslT, WslT, bi, bf, bo, bc, be, Hbuf32, Hmir, out);
}

// Round 15
// 1649.501 us; speedup vs baseline: 1.4041x; 1.2332x over previous
//
#include <hip/hip_runtime.h>
#include <hip/hip_bf16.h>

typedef unsigned short ushortT;
typedef __attribute__((ext_vector_type(8))) short bf16x8;
typedef __attribute__((ext_vector_type(4))) float f32x4;
typedef __attribute__((ext_vector_type(4))) int i32x4;

#define B_SZ 64
#define T_SZ 512
#define D_SZ 256
#define U_SZ 512
#define M_SZ 64

// ---------- helpers ----------
__device__ __forceinline__ ushortT f2b(float f) {
    __hip_bfloat16 h = __float2bfloat16(f);
    union { __hip_bfloat16 h; ushortT u; } c; c.h = h; return c.u;
}
__device__ __forceinline__ float clip10(float v) {
    return fminf(fmaxf(v, -10.f), 10.f);
}
__device__ __forceinline__ float tanh_fast(float z) {
    float e = __expf(2.f * z);
    return 1.f - 2.f / (e + 1.f);   // inf-safe
}
__device__ __forceinline__ float sigm_fast(float z) {
    return 1.f / (1.f + __expf(-z));
}

// ---------- prep: x -> clipped bf16 ----------
__global__ void prep_xb_k(const float* __restrict__ x, ushortT* __restrict__ xb) {
    const int n4 = (B_SZ * T_SZ * D_SZ) / 4;
    for (int i = blockIdx.x * blockDim.x + threadIdx.x; i < n4; i += gridDim.x * blockDim.x) {
        float4 v = ((const float4*)x)[i];
        ushort4 o;
        o.x = f2b(clip10(v.x));
        o.y = f2b(clip10(v.y));
        o.z = f2b(clip10(v.z));
        o.w = f2b(clip10(v.w));
        ((ushort4*)xb)[i] = o;
    }
}

// ---------- prep: U^T and W^T bf16 (transposed, col-major rows) ----------
// UslT cols: 0..2047 gate U cols, 2048..2111 Ue cols.
// WslT cols: 0..2047 gate W cols, 2048..2111 We cols, 2112..2623 Wm cols.
__global__ void prep_uw_k(const float* __restrict__ Ui, const float* __restrict__ Uf,
                          const float* __restrict__ Uo, const float* __restrict__ Uc,
                          const float* __restrict__ Ue,
                          const float* __restrict__ Wi, const float* __restrict__ Wf,
                          const float* __restrict__ Wo, const float* __restrict__ Wc,
                          const float* __restrict__ We, const float* __restrict__ Wm,
                          ushortT* __restrict__ UslT, ushortT* __restrict__ WslT) {
    const int NU = 2112 * 512;
    const int NW = 2624 * 256;
    for (int i = blockIdx.x * blockDim.x + threadIdx.x; i < NU + NW; i += gridDim.x * blockDim.x) {
        if (i < NU) {
            int c = i >> 9, k = i & 511;
            float v;
            if (c < 2048) {
                int g = c >> 9, u = c & 511;
                const float* U = (g == 0) ? Ui : (g == 1) ? Uf : (g == 2) ? Uo : Uc;
                v = U[k * 512 + u];
            } else {
                v = Ue[k * 64 + (c - 2048)];
            }
            UslT[i] = f2b(v);
        } else {
            int j = i - NU;
            int c = j >> 8, k = j & 255;
            float v;
            if (c < 2048) {
                int g = c >> 9, u = c & 511;
                const float* W = (g == 0) ? Wi : (g == 1) ? Wf : (g == 2) ? Wo : Wc;
                v = W[k * 512 + u];
            } else if (c < 2112) {
                v = We[k * 64 + (c - 2048)];
            } else {
                v = Wm[k * 512 + (c - 2112)];
            }
            WslT[j] = f2b(v);
        }
    }
}

#define MEMF_PB 1096   // floats per batch block (16 rows x 68 + 8 skew)
#define MEMF_ROW 68

// ---------- persistent recurrent kernel ----------
// Structure = R14 minus the sentinel phase and S0: detection IS the bulk read.
// Each wave speculatively bulk-reads its own 64B line from the L2 mirror and
// validates all 16 tags (tag<<16|bf16 self-validating words); on failure it
// alternates mirror/LLC re-reads. The LLC copy guarantees progress under any
// WG->XCD placement (G16); the mirror is advisory-fast-path only.
// 2 barriers/step (S1 h-tile staged, S2 gates ready). All waves symmetric in
// the receive path; waves 1,2 do the pointwise+release (dual store).
__global__ __launch_bounds__(256, 1) void xlstm_rec(
    const ushortT* __restrict__ xb,    // [B*T][256] bf16 (clipped)
    const ushortT* __restrict__ UslT,  // [2112][512] bf16
    const ushortT* __restrict__ WslT,  // [2624][256] bf16
    const float* __restrict__ bi_p, const float* __restrict__ bf_p,
    const float* __restrict__ bo_p, const float* __restrict__ bc_p,
    const float* __restrict__ be_p,
    unsigned* __restrict__ Hbuf32,     // [2][64][512] u32 tagged h (LLC copy)
    unsigned* __restrict__ Hmir,       // [2][64][512] u32 tagged h (L2 mirror)
    float* __restrict__ out)           // [64][512][512] fp32
{
    const int bid = blockIdx.x, tid = threadIdx.x;
    const int grp = bid & 7, rank = bid >> 3;
    const int wave = tid >> 6, lane = tid & 63;
    const int b0 = grp << 3;     // batch base
    const int u0 = rank << 4;    // unit base

    __shared__ float memF[8 * MEMF_PB];     // c ring: [pb][pu][slot(64)+pad] (thread-private rows)
    __shared__ float g_lds[4][8][16];       // i,f,o,ctilde
    __shared__ float e_lds[8][68];          // raw clipped e-logits (logical idx)
    __shared__ float w_lds[8][72];          // softmax numerators (physical slot)
    __shared__ float zm_lds[8][16];         // x_t @ Wm slice
    __shared__ ushortT hLb[8][520];         // h tile bf16, padded stride (1040B)

    for (int i = tid; i < 8 * MEMF_PB; i += 256) memF[i] = 0.f;

    // ---- register-resident weight B-fragments ----
    int cols[2];
    float biasv[2];
#pragma unroll
    for (int nt = 0; nt < 2; ++nt) {
        int j = wave * 32 + nt * 16 + (lane & 15);
        if (j < 64) {
            int g = j >> 4, u = u0 + (j & 15);
            cols[nt] = g * 512 + u;
            biasv[nt] = (g == 0) ? bi_p[u] : (g == 1) ? bf_p[u] : (g == 2) ? bo_p[u] : bc_p[u];
        } else {
            cols[nt] = 2048 + (j - 64);
            biasv[nt] = be_p[j - 64];
        }
    }
    const int koct = (lane >> 4) * 8;
    bf16x8 B1[2][8], B2[2][16], B1m[8];
#pragma unroll
    for (int nt = 0; nt < 2; ++nt) {
        const ushortT* bw = WslT + cols[nt] * 256;
#pragma unroll
        for (int kt = 0; kt < 8; ++kt)
            B1[nt][kt] = *(const bf16x8*)(bw + kt * 32 + koct);
        const ushortT* bu = UslT + cols[nt] * 512;
#pragma unroll
        for (int kt = 0; kt < 16; ++kt)
            B2[nt][kt] = *(const bf16x8*)(bu + kt * 32 + koct);
    }
    if (wave == 1) {   // Wm fragment (zm = x@Wm via MFMA)
        const ushortT* bm = WslT + (2112 + u0 + (lane & 15)) * 256;
#pragma unroll
        for (int kt = 0; kt < 8; ++kt)
            B1m[kt] = *(const bf16x8*)(bm + kt * 32 + koct);
    }

    const int arow = lane & 7;                 // MFMA A-operand batch row
    const bool is_pw = (tid >= 64 && tid < 192);
    const int pb = (tid - 64) >> 4;
    const int pu = (tid - 64) & 15;
    // bulk tagged-h fetch: wave w owns rows 2w (lanes<32), 2w+1 (lanes>=32)
    const int prow = 2 * wave + (lane >> 5);
    const int pcol = (lane & 31) * 16;         // 16 u32 units per lane (one 64B line)

    __syncthreads();

    for (int t = 0; t < T_SZ; ++t) {
        const int par = t & 1, wpar = (t + 1) & 1;
        const unsigned T16 = ((unsigned)t) << 16;

        // ---- phase A: issue a1f x-fragment loads ----
        i32x4 a1f[8];
        {
            const ushortT* xrow = xb + ((b0 + arow) * T_SZ + t) * D_SZ + koct;
#pragma unroll
            for (int kt = 0; kt < 8; ++kt)
                asm volatile("global_load_dwordx4 %0, %1, off"
                             : "=v"(a1f[kt]) : "v"(xrow + kt * 32) : "memory");
        }

        // ---- phase B: speculative bulk read (mirror) — detection IS the read ----
        const unsigned* msrc = Hmir + (par << 15) + (b0 + prow) * 512 + pcol;
        const unsigned* hsrc = Hbuf32 + (par << 15) + (b0 + prow) * 512 + pcol;
        i32x4 g0, g1, g2, g3;
        asm volatile("global_load_dwordx4 %0, %4, off sc0\n\t"
                     "global_load_dwordx4 %1, %4, off offset:16 sc0\n\t"
                     "global_load_dwordx4 %2, %4, off offset:32 sc0\n\t"
                     "global_load_dwordx4 %3, %4, off offset:48 sc0"
                     : "=v"(g0), "=v"(g1), "=v"(g2), "=v"(g3)
                     : "v"(msrc) : "memory");
        // wait until only the 4 bulk loads remain -> a1f + older F stores done
        asm volatile("s_waitcnt vmcnt(4)"
                     : "+v"(a1f[0]), "+v"(a1f[1]), "+v"(a1f[2]), "+v"(a1f[3]),
                       "+v"(a1f[4]), "+v"(a1f[5]), "+v"(a1f[6]), "+v"(a1f[7])
                     :: "memory");
        __builtin_amdgcn_sched_barrier(0);

        // ---- x-MFMAs hide the bulk-read latency ----
        f32x4 acc0 = {0.f, 0.f, 0.f, 0.f}, acc1 = {0.f, 0.f, 0.f, 0.f};
        f32x4 acc2 = {0.f, 0.f, 0.f, 0.f};
#pragma unroll
        for (int kt = 0; kt < 8; ++kt) {
            bf16x8 a = __builtin_bit_cast(bf16x8, a1f[kt]);
            acc0 = __builtin_amdgcn_mfma_f32_16x16x32_bf16(a, B1[0][kt], acc0, 0, 0, 0);
            acc1 = __builtin_amdgcn_mfma_f32_16x16x32_bf16(a, B1[1][kt], acc1, 0, 0, 0);
        }
        if (wave == 1) {
#pragma unroll
            for (int kt = 0; kt < 8; ++kt) {
                bf16x8 a = __builtin_bit_cast(bf16x8, a1f[kt]);
                acc2 = __builtin_amdgcn_mfma_f32_16x16x32_bf16(a, B1m[kt], acc2, 0, 0, 0);
            }
        }

        // ---- validate loop: tags==t? retry alternating LLC/mirror ----
        {
            unsigned it = 0;
            while (true) {
                asm volatile("s_waitcnt vmcnt(0)"
                             : "+v"(g0), "+v"(g1), "+v"(g2), "+v"(g3) :: "memory");
                unsigned d = (((unsigned)g0[0] ^ T16) | ((unsigned)g0[1] ^ T16)) |
                             (((unsigned)g0[2] ^ T16) | ((unsigned)g0[3] ^ T16));
                d |= (((unsigned)g1[0] ^ T16) | ((unsigned)g1[1] ^ T16)) |
                     (((unsigned)g1[2] ^ T16) | ((unsigned)g1[3] ^ T16));
                d |= (((unsigned)g2[0] ^ T16) | ((unsigned)g2[1] ^ T16)) |
                     (((unsigned)g2[2] ^ T16) | ((unsigned)g2[3] ^ T16));
                d |= (((unsigned)g3[0] ^ T16) | ((unsigned)g3[1] ^ T16)) |
                     (((unsigned)g3[2] ^ T16) | ((unsigned)g3[3] ^ T16));
                if (__all((d & 0xFFFF0000u) == 0u)) break;
                if ((it & 1u) == 0u) {   // LLC (authoritative, guarantees progress)
                    asm volatile("global_load_dwordx4 %0, %4, off sc0 sc1\n\t"
                                 "global_load_dwordx4 %1, %4, off offset:16 sc0 sc1\n\t"
                                 "global_load_dwordx4 %2, %4, off offset:32 sc0 sc1\n\t"
                                 "global_load_dwordx4 %3, %4, off offset:48 sc0 sc1"
                                 : "=v"(g0), "=v"(g1), "=v"(g2), "=v"(g3)
                                 : "v"(hsrc) : "memory");
                } else {                 // mirror (L2-local fast path)
                    asm volatile("global_load_dwordx4 %0, %4, off sc0\n\t"
                                 "global_load_dwordx4 %1, %4, off offset:16 sc0\n\t"
                                 "global_load_dwordx4 %2, %4, off offset:32 sc0\n\t"
                                 "global_load_dwordx4 %3, %4, off offset:48 sc0"
                                 : "=v"(g0), "=v"(g1), "=v"(g2), "=v"(g3)
                                 : "v"(msrc) : "memory");
                }
                ++it;
            }
        }
        __builtin_amdgcn_sched_barrier(0);

        // ---- phase C: strip tags, pack bf16 pairs, stage into LDS ----
        {
            unsigned p0 = ((unsigned)g0[0] & 0xFFFFu) | ((unsigned)g0[1] << 16);
            unsigned p1 = ((unsigned)g0[2] & 0xFFFFu) | ((unsigned)g0[3] << 16);
            unsigned p2 = ((unsigned)g1[0] & 0xFFFFu) | ((unsigned)g1[1] << 16);
            unsigned p3 = ((unsigned)g1[2] & 0xFFFFu) | ((unsigned)g1[3] << 16);
            unsigned p4 = ((unsigned)g2[0] & 0xFFFFu) | ((unsigned)g2[1] << 16);
            unsigned p5 = ((unsigned)g2[2] & 0xFFFFu) | ((unsigned)g2[3] << 16);
            unsigned p6 = ((unsigned)g3[0] & 0xFFFFu) | ((unsigned)g3[1] << 16);
            unsigned p7 = ((unsigned)g3[2] & 0xFFFFu) | ((unsigned)g3[3] << 16);
            i32x4 P0 = {(int)p0, (int)p1, (int)p2, (int)p3};
            i32x4 P1 = {(int)p4, (int)p5, (int)p6, (int)p7};
            *(i32x4*)&hLb[prow][pcol] = P0;
            *(i32x4*)&hLb[prow][pcol + 8] = P1;
        }
        __syncthreads();   // S1: h tile staged

        // ---- phase D: h-MFMAs from LDS ----
#pragma unroll
        for (int kt = 0; kt < 16; ++kt) {
            bf16x8 a = *(const bf16x8*)&hLb[arow][kt * 32 + koct];
            acc0 = __builtin_amdgcn_mfma_f32_16x16x32_bf16(a, B2[0][kt], acc0, 0, 0, 0);
            acc1 = __builtin_amdgcn_mfma_f32_16x16x32_bf16(a, B2[1][kt], acc1, 0, 0, 0);
        }

        // ---- phase E: epilogue (C/D: col=lane&15, row=(lane>>4)*4+i; rows 0..7 in lanes<32) ----
        if (lane < 32) {
#pragma unroll
            for (int nt = 0; nt < 2; ++nt) {
                int j = wave * 32 + nt * 16 + (lane & 15);
                f32x4 a = nt ? acc1 : acc0;
#pragma unroll
                for (int i = 0; i < 4; ++i) {
                    int b = ((lane >> 4) << 2) + i;
                    float z = clip10(a[i] + biasv[nt]);
                    if (j < 64) {
                        int g = j >> 4;
                        g_lds[g][b][j & 15] = (g == 3) ? tanh_fast(z) : sigm_fast(z);
                    } else {
                        e_lds[b][j - 64] = z;
                    }
                }
            }
            if (wave == 1) {
#pragma unroll
                for (int i = 0; i < 4; ++i)
                    zm_lds[((lane >> 4) << 2) + i][lane & 15] = acc2[i];
            }
        }
        __syncthreads();   // S2: gates/e/zm ready

        // ---- phase F: pointwise + dual tagged-h release (waves 1,2) ----
        if (is_pw) {
            // max-free softmax numerators (|e|<=10 -> exp safe in fp32)
            const int base = pu * 4;
            const int k0 = t - 1 - base;
            float wv0 = __expf(e_lds[pb][(unsigned)(k0) & 63]);
            float wv1 = __expf(e_lds[pb][(unsigned)(k0 - 1) & 63]);
            float wv2 = __expf(e_lds[pb][(unsigned)(k0 - 2) & 63]);
            float wv3 = __expf(e_lds[pb][(unsigned)(k0 - 3) & 63]);
            float ssum = (wv0 + wv1) + (wv2 + wv3);
#pragma unroll
            for (int d = 1; d < 16; d <<= 1) ssum += __shfl_xor(ssum, d);
            float4 wq = {wv0, wv1, wv2, wv3};
            *(float4*)&w_lds[pb][base] = wq;
            asm volatile("" ::: "memory");   // keep ds_write before ds_reads
            float attn = 0.f;
            const float4* wr = (const float4*)&w_lds[pb][0];
            const float4* mr = (const float4*)&memF[pb * MEMF_PB + pu * MEMF_ROW];
#pragma unroll
            for (int p4i = 0; p4i < 16; ++p4i) {
                float4 w4 = wr[p4i], m4 = mr[p4i];
                attn = fmaf(w4.x, m4.x, attn);
                attn = fmaf(w4.y, m4.y, attn);
                attn = fmaf(w4.z, m4.z, attn);
                attn = fmaf(w4.w, m4.w, attn);
            }
            attn /= ssum;
            float ig = g_lds[0][pb][pu];
            float fg = g_lds[1][pb][pu];
            float og = g_lds[2][pb][pu];
            float ct = g_lds[3][pb][pu];
            float c = fg * (attn + zm_lds[pb][pu]) + ig * ct;
            float h = og * tanh_fast(c);
            // dual tagged-h release: mirror (L2) first, then authoritative LLC
            unsigned tagval = (((unsigned)(t + 1)) << 16) | (unsigned)f2b(h);
            const unsigned off = (unsigned)((wpar << 15) + (b0 + pb) * 512 + u0 + pu);
            asm volatile("global_store_dword %0, %1, off sc0"
                         :: "v"(Hmir + off), "v"(tagval) : "memory");
            asm volatile("global_store_dword %0, %1, off sc0 sc1"
                         :: "v"(Hbuf32 + off), "v"(tagval) : "memory");
            // off-critical-path writes (acks drained by next step's vmcnt(4))
            const float* oaddr = out + ((b0 + pb) * T_SZ + t) * U_SZ + u0 + pu;
            asm volatile("global_store_dword %0, %1, off"
                         :: "v"(oaddr), "v"(h) : "memory");
            memF[pb * MEMF_PB + pu * MEMF_ROW + (t & 63)] = c;
        }
        // no end barrier: S1(t+1) separates C(t+1) hLb writes from D(t) reads;
        // F(t) g/e/zm readers precede S1(t+1) which precedes E(t+1) writers.
        // memF/w_lds rows are wave-private.
    }
}

// ---------- launch ----------
extern "C" void kernel_launch(void* const* d_in, const int* in_sizes, int n_in,
                              void* d_out, int out_size, void* d_ws, size_t ws_size,
                              hipStream_t stream) {
    const float* x  = (const float*)d_in[0];
    const float* Wi = (const float*)d_in[1];
    const float* Ui = (const float*)d_in[2];
    const float* bi = (const float*)d_in[3];
    const float* Wf = (const float*)d_in[4];
    const float* Uf = (const float*)d_in[5];
    const float* bf = (const float*)d_in[6];
    const float* Wo = (const float*)d_in[7];
    const float* Uo = (const float*)d_in[8];
    const float* bo = (const float*)d_in[9];
    const float* Wc = (const float*)d_in[10];
    const float* Uc = (const float*)d_in[11];
    const float* bc = (const float*)d_in[12];
    const float* Wm = (const float*)d_in[13];
    const float* We = (const float*)d_in[14];
    const float* Ue = (const float*)d_in[15];
    const float* be = (const float*)d_in[16];

    char* ws = (char*)d_ws;
    const size_t off_xb    = 0;
    const size_t off_uslt  = off_xb + (size_t)B_SZ * T_SZ * D_SZ * 2;   // 16,777,216
    const size_t off_wslt  = off_uslt + (size_t)2112 * 512 * 2;         // +2,162,688
    const size_t off_hbuf  = off_wslt + (size_t)2624 * 256 * 2;         // +1,343,488
    const size_t off_hmir  = off_hbuf + 262144;
    ushortT* xb       = (ushortT*)(ws + off_xb);
    ushortT* UslT     = (ushortT*)(ws + off_uslt);
    ushortT* WslT     = (ushortT*)(ws + off_wslt);
    unsigned* Hbuf32  = (unsigned*)(ws + off_hbuf);   // 2*64*512*4 = 262,144 B
    unsigned* Hmir    = (unsigned*)(ws + off_hmir);   // 262,144 B
    float* out = (float*)d_out;

    // zero both tagged-h double buffers (tags -> 0) — re-zeroed every replay
    (void)hipMemsetAsync(ws + off_hbuf, 0, 524288, stream);

    prep_xb_k<<<2048, 256, 0, stream>>>(x, xb);
    prep_uw_k<<<2048, 256, 0, stream>>>(Ui, Uf, Uo, Uc, Ue, Wi, Wf, Wo, Wc, We, Wm,
                                        UslT, WslT);

    xlstm_rec<<<dim3(256), dim3(256), 0, stream>>>(
        xb, UslT, WslT, bi, bf, bo, bc, be, Hbuf32, Hmir, out);
}